// Round 1
// baseline (153.733 us; speedup 1.0000x reference)
//
#include <hip/hip_runtime.h>
#include <math.h>

// Problem constants (setup_inputs: S=2048, U=10, D=256)
#define SS   2048
#define UU   10
#define DD   256
#define BB   (SS * UU)   // 20480 rows
#define EPSF 1e-8f

typedef __attribute__((ext_vector_type(8))) short   bf16x8;
typedef __attribute__((ext_vector_type(4))) float   floatx4;

__device__ static inline unsigned short f2bf(float f) {
    union { float f; unsigned u; } v; v.f = f;
    unsigned r = (v.u + 0x7FFFu + ((v.u >> 16) & 1u)) >> 16;  // RNE
    return (unsigned short)r;
}

__device__ static inline void gl_lds16(const unsigned short* g, unsigned short* l) {
    // 16B per lane; LDS dest = wave-uniform base + lane*16
    __builtin_amdgcn_global_load_lds((const __attribute__((address_space(1))) void*)g,
                                     (__attribute__((address_space(3))) void*)l, 16, 0, 0);
}

// ---- Kernel 1 (fused prep): normalize rows -> Enb, centroid+normalize -> Cnb,
//      zero sumexp (and out) so no memset dispatch is needed ----
__global__ __launch_bounds__(256) void prep_kernel(const float* __restrict__ E,
                                                   unsigned short* __restrict__ Enb,
                                                   unsigned short* __restrict__ Cnb,
                                                   float* __restrict__ sumexp,
                                                   float* __restrict__ out) {
    const int s   = blockIdx.x;
    const int wid = threadIdx.x >> 6, lane = threadIdx.x & 63;
    __shared__ float cent[4][256];
    __shared__ float sred[256];

    if (threadIdx.x < UU) sumexp[s * UU + threadIdx.x] = 0.f;
    if (s == 0 && threadIdx.x == 0) out[0] = 0.f;

    float cp0 = 0.f, cp1 = 0.f, cp2 = 0.f, cp3 = 0.f;
    for (int u = wid; u < UU; u += 4) {
        const size_t roff = (size_t)(s * UU + u) * DD;
        float4 v = ((const float4*)(E + roff))[lane];
        float ssq = v.x * v.x + v.y * v.y + v.z * v.z + v.w * v.w;
#pragma unroll
        for (int off = 32; off; off >>= 1) ssq += __shfl_xor(ssq, off, 64);
        const float rinv = 1.0f / fmaxf(sqrtf(ssq), EPSF);
        ushort4 o;
        o.x = f2bf(v.x * rinv); o.y = f2bf(v.y * rinv);
        o.z = f2bf(v.z * rinv); o.w = f2bf(v.w * rinv);
        ((ushort4*)(Enb + roff))[lane] = o;
        cp0 += v.x; cp1 += v.y; cp2 += v.z; cp3 += v.w;
    }
    cent[wid][lane * 4 + 0] = cp0;
    cent[wid][lane * 4 + 1] = cp1;
    cent[wid][lane * 4 + 2] = cp2;
    cent[wid][lane * 4 + 3] = cp3;
    __syncthreads();

    const int d = threadIdx.x;
    const float c = (cent[0][d] + cent[1][d] + cent[2][d] + cent[3][d]) * 0.1f;
    sred[d] = c * c;
    __syncthreads();
#pragma unroll
    for (int off = 128; off; off >>= 1) {
        if (d < off) sred[d] += sred[d + off];
        __syncthreads();
    }
    const float rinv = 1.0f / fmaxf(sqrtf(sred[0]), EPSF);
    Cnb[(size_t)s * DD + d] = f2bf(c * rinv);
}

// ---- Kernel 2: bf16 MFMA GEMM (Enb x Cnb^T) fused with exp-sum + pos ----
// NEW STRUCTURE (full-K LDS, counted-vmcnt pipeline):
//   K=256 fits entirely in LDS: As/Bs = 8 chunks x [128 rows x 32k] = 64 KB each
//   (128 KB total -> 1 block/CU). ALL 32 staging loads per wave are issued in
//   the prologue (8-deep chunk pipeline in the VMEM queue); each 32-K chunk
//   then does s_waitcnt vmcnt(28-4*ck) + raw s_barrier + 16 MFMAs. No
//   __syncthreads in the loop -> no vmcnt(0) drain until the final chunk.
//   Fragment layout / swizzle identical to the verified round-2 kernel
//   (SQ_LDS_BANK_CONFLICT == 0): granule g of row r stored at slot g^((r>>1)&3).
#define BM 128
#define BN 128
#define BK 32
#define NCK 8            // DD / BK

__device__ __forceinline__ void chunk_mfma(const unsigned short* Ab,
                                           const unsigned short* Bb,
                                           const int* aoff, const int* boff,
                                           floatx4 (&acc)[4][4]) {
    bf16x8 af[4], bfr[4];
#pragma unroll
    for (int t = 0; t < 4; ++t) af[t]  = *(const bf16x8*)(Ab + aoff[t]);
#pragma unroll
    for (int t = 0; t < 4; ++t) bfr[t] = *(const bf16x8*)(Bb + boff[t]);
#pragma unroll
    for (int mt = 0; mt < 4; ++mt)
#pragma unroll
        for (int nt = 0; nt < 4; ++nt)
            acc[mt][nt] = __builtin_amdgcn_mfma_f32_16x16x32_bf16(af[mt], bfr[nt], acc[mt][nt], 0, 0, 0);
}

__global__ __launch_bounds__(256) void gemm_lse_kernel(const unsigned short* __restrict__ Enb,
                                                       const unsigned short* __restrict__ Cnb,
                                                       float* __restrict__ posArr,
                                                       float* __restrict__ sumexp) {
    __shared__ unsigned short As[NCK * BM * BK];   // 64 KB: chunk ck at As + ck*4096
    __shared__ unsigned short Bs[NCK * BN * BK];   // 64 KB

    const int tid  = threadIdx.x;
    const int wid  = tid >> 6, lane = tid & 63;
    const int l15  = lane & 15, quad = lane >> 4;
    const int wave_m = wid >> 1, wave_n = wid & 1;

    // XCD-aware bijective swizzle: grid 2560 = 8 XCDs x 320 contiguous blocks.
    // Within an XCD, bn runs fastest -> each 64KB A-panel is fetched into ONE
    // XCD's L2 and reused 16x; all B panels (1 MB) stay L2-resident.
    const int swz = (blockIdx.x & 7) * 320 + (blockIdx.x >> 3);
    const int bn = swz & 15;                 // SS/BN = 16
    const int bm = swz >> 4;                 // BB/BM = 160
    const int row0 = bm * BM, n0 = bn * BN;

    // staging map (per chunk): 16 sub-chunks of 1 KB (16 rows x 32k);
    // A: c=0..7, B: c=8..15; 4 per wave. lane -> row rl=lane>>2, slot sl=lane&3;
    // fetch logical granule sl^((rl>>1)&3) (pre-swizzled global source,
    // linear LDS dest -> both-sides-consistent with the fragment-read swizzle).
    const int rl = lane >> 2;
    const int gf = ((lane & 3) ^ ((rl >> 1) & 3)) * 8;
    const unsigned short* gp[4];
    unsigned short* lp[4];
#pragma unroll
    for (int i = 0; i < 4; ++i) {
        const int c = wid * 4 + i;
        if (c < 8) {
            gp[i] = Enb + (size_t)(row0 + c * 16 + rl) * DD + gf;
            lp[i] = As + c * 512;
        } else {
            gp[i] = Cnb + (size_t)(n0 + (c - 8) * 16 + rl) * DD + gf;
            lp[i] = Bs + (c - 8) * 512;
        }
    }

    // ---- prologue: issue ALL staging loads, chunk-major (4 calls/wave/chunk,
    // 32 total/wave; vmcnt queue holds them all) ----
#pragma unroll
    for (int ck = 0; ck < NCK; ++ck) {
#pragma unroll
        for (int i = 0; i < 4; ++i)
            gl_lds16(gp[i] + ck * BK, lp[i] + ck * (BM * BK));
    }

    // fragment offsets (within a chunk): row r = wtile*16 + l15,
    // elem = r*BK + (quad^((l15>>1)&3))*8  -- verified conflict-free
    const int fswz = (quad ^ ((l15 >> 1) & 3)) * 8;
    int aoff[4], boff[4];
#pragma unroll
    for (int t = 0; t < 4; ++t) {
        aoff[t] = (wave_m * 64 + t * 16 + l15) * BK + fswz;
        boff[t] = (wave_n * 64 + t * 16 + l15) * BK + fswz;
    }

    floatx4 acc[4][4];
#pragma unroll
    for (int i = 0; i < 4; ++i)
#pragma unroll
        for (int j = 0; j < 4; ++j) acc[i][j] = (floatx4){0.f, 0.f, 0.f, 0.f};

    // ---- chunk loop: counted vmcnt (own 4 loads for chunk ck drained) +
    // raw barrier (all waves' loads for chunk ck drained). sched_barrier(0)
    // pins the ds_reads after the barrier (rule #18-style hazard). ----
#define STEP(CK, VM)                                                        \
    asm volatile("s_waitcnt vmcnt(" #VM ")" ::: "memory");                  \
    __builtin_amdgcn_s_barrier();                                           \
    __builtin_amdgcn_sched_barrier(0);                                      \
    chunk_mfma(As + (CK) * (BM * BK), Bs + (CK) * (BN * BK), aoff, boff, acc);

    STEP(0, 28) STEP(1, 24) STEP(2, 20) STEP(3, 16)
    STEP(4, 12) STEP(5, 8)  STEP(6, 4)  STEP(7, 0)
#undef STEP

    // epilogue: C/D layout col=l15 (n), row=quad*4+reg (m) -- unchanged
#pragma unroll
    for (int mt = 0; mt < 4; ++mt) {
        float rs[4] = {0.f, 0.f, 0.f, 0.f};
        const int growb = row0 + wave_m * 64 + mt * 16 + quad * 4;
#pragma unroll
        for (int nt = 0; nt < 4; ++nt) {
            const int col = n0 + wave_n * 64 + nt * 16 + l15;
#pragma unroll
            for (int r = 0; r < 4; ++r) {
                const int grow = growb + r;
                const float sim = acc[mt][nt][r];
                if (col == grow / UU) {
                    posArr[grow] = sim;           // excluded from sum (-inf mask)
                } else {
                    rs[r] += __expf(sim);
                }
            }
        }
#pragma unroll
        for (int m = 1; m < 16; m <<= 1) {
#pragma unroll
            for (int r = 0; r < 4; ++r) rs[r] += __shfl_xor(rs[r], m, 64);
        }
        if (l15 == 0) {
#pragma unroll
            for (int r = 0; r < 4; ++r) atomicAdd(&sumexp[growb + r], rs[r]);
        }
    }
}

// ---- Kernel 3: single-pass finalize: mean of (-pos + log(sumexp)) ----
__global__ __launch_bounds__(256) void finalize_kernel(const float* __restrict__ posArr,
                                                       const float* __restrict__ sumexp,
                                                       float* __restrict__ out) {
    __shared__ float sred[256];
    const int tid = threadIdx.x;
    const int r = blockIdx.x * 256 + tid;
    sred[tid] = logf(sumexp[r]) - posArr[r];
    __syncthreads();
#pragma unroll
    for (int off = 128; off; off >>= 1) {
        if (tid < off) sred[tid] += sred[tid + off];
        __syncthreads();
    }
    if (tid == 0) atomicAdd(out, sred[0] * (1.0f / (float)BB));
}

extern "C" void kernel_launch(void* const* d_in, const int* in_sizes, int n_in,
                              void* d_out, int out_size, void* d_ws, size_t ws_size,
                              hipStream_t stream) {
    const float* E = (const float*)d_in[0];
    float* out = (float*)d_out;

    unsigned short* Enb = (unsigned short*)d_ws;            // BB*DD bf16 = 10.5 MB
    unsigned short* Cnb = Enb + (size_t)BB * DD;            // SS*DD bf16 = 1 MB
    float* posArr = (float*)(Cnb + (size_t)SS * DD);        // BB floats
    float* sumexp = posArr + BB;                            // BB floats (zeroed by prep)

    prep_kernel<<<SS, 256, 0, stream>>>(E, Enb, Cnb, sumexp, out);
    gemm_lse_kernel<<<(BB / BM) * (SS / BN), 256, 0, stream>>>(Enb, Cnb, posArr, sumexp);
    finalize_kernel<<<BB / 256, 256, 0, stream>>>(posArr, sumexp, out);
}

// Round 2
// 120.384 us; speedup vs baseline: 1.2770x; 1.2770x over previous
//
#include <hip/hip_runtime.h>
#include <math.h>

// Problem constants (setup_inputs: S=2048, U=10, D=256)
#define SS   2048
#define UU   10
#define DD   256
#define BB   (SS * UU)   // 20480 rows
#define EPSF 1e-8f

typedef __attribute__((ext_vector_type(8))) short   bf16x8;
typedef __attribute__((ext_vector_type(4))) float   floatx4;

__device__ static inline unsigned short f2bf(float f) {
    union { float f; unsigned u; } v; v.f = f;
    unsigned r = (v.u + 0x7FFFu + ((v.u >> 16) & 1u)) >> 16;  // RNE
    return (unsigned short)r;
}

__device__ static inline void gl_lds16(const unsigned short* g, unsigned short* l) {
    // 16B per lane; LDS dest = wave-uniform base + lane*16
    __builtin_amdgcn_global_load_lds((const __attribute__((address_space(1))) void*)g,
                                     (__attribute__((address_space(3))) void*)l, 16, 0, 0);
}

// ---- Kernel 1 (fused prep): normalize rows -> Enb, centroid+normalize -> Cnb,
//      zero sumexp (and out) so no memset dispatch is needed ----
__global__ __launch_bounds__(256) void prep_kernel(const float* __restrict__ E,
                                                   unsigned short* __restrict__ Enb,
                                                   unsigned short* __restrict__ Cnb,
                                                   float* __restrict__ sumexp,
                                                   float* __restrict__ out) {
    const int s   = blockIdx.x;
    const int wid = threadIdx.x >> 6, lane = threadIdx.x & 63;
    __shared__ float cent[4][256];
    __shared__ float sred[256];

    if (threadIdx.x < UU) sumexp[s * UU + threadIdx.x] = 0.f;
    if (s == 0 && threadIdx.x == 0) out[0] = 0.f;

    float cp0 = 0.f, cp1 = 0.f, cp2 = 0.f, cp3 = 0.f;
    for (int u = wid; u < UU; u += 4) {
        const size_t roff = (size_t)(s * UU + u) * DD;
        float4 v = ((const float4*)(E + roff))[lane];
        float ssq = v.x * v.x + v.y * v.y + v.z * v.z + v.w * v.w;
#pragma unroll
        for (int off = 32; off; off >>= 1) ssq += __shfl_xor(ssq, off, 64);
        const float rinv = 1.0f / fmaxf(sqrtf(ssq), EPSF);
        ushort4 o;
        o.x = f2bf(v.x * rinv); o.y = f2bf(v.y * rinv);
        o.z = f2bf(v.z * rinv); o.w = f2bf(v.w * rinv);
        ((ushort4*)(Enb + roff))[lane] = o;
        cp0 += v.x; cp1 += v.y; cp2 += v.z; cp3 += v.w;
    }
    cent[wid][lane * 4 + 0] = cp0;
    cent[wid][lane * 4 + 1] = cp1;
    cent[wid][lane * 4 + 2] = cp2;
    cent[wid][lane * 4 + 3] = cp3;
    __syncthreads();

    const int d = threadIdx.x;
    const float c = (cent[0][d] + cent[1][d] + cent[2][d] + cent[3][d]) * 0.1f;
    sred[d] = c * c;
    __syncthreads();
#pragma unroll
    for (int off = 128; off; off >>= 1) {
        if (d < off) sred[d] += sred[d + off];
        __syncthreads();
    }
    const float rinv = 1.0f / fmaxf(sqrtf(sred[0]), EPSF);
    Cnb[(size_t)s * DD + d] = f2bf(c * rinv);
}

// ---- Kernel 2: bf16 MFMA GEMM (Enb x Cnb^T) fused with exp-sum + pos ----
// Round-2 structure: round-0 verified core (128x128 block, 2x2 waves, 4x4
// tiles of 16x16x32, BK=32, swizzled LDS granules) + minimum 2-phase
// double-buffer (T3 recipe): stage chunk t+1 BEFORE computing chunk t, ONE
// __syncthreads per step (its implicit vmcnt(0) drain lands after compute has
// covered the load latency). 32 KB LDS -> ~4 blocks/CU co-resident (the fill
// concurrency round-1's 128 KB/1-block version destroyed). XCD-bijective
// block swizzle kept (FETCH 41.5 -> 9.3 MB, measured round 1).
#define BM 128
#define BN 128
#define BK 32
#define NCK 8            // DD / BK
#define CHUNK (BM * BK)  // 4096 shorts = 8 KB per buffer per operand

__device__ __forceinline__ void chunk_mfma(const unsigned short* Ab,
                                           const unsigned short* Bb,
                                           const int* aoff, const int* boff,
                                           floatx4 (&acc)[4][4]) {
    bf16x8 af[4], bfr[4];
#pragma unroll
    for (int t = 0; t < 4; ++t) af[t]  = *(const bf16x8*)(Ab + aoff[t]);
#pragma unroll
    for (int t = 0; t < 4; ++t) bfr[t] = *(const bf16x8*)(Bb + boff[t]);
#pragma unroll
    for (int mt = 0; mt < 4; ++mt)
#pragma unroll
        for (int nt = 0; nt < 4; ++nt)
            acc[mt][nt] = __builtin_amdgcn_mfma_f32_16x16x32_bf16(af[mt], bfr[nt], acc[mt][nt], 0, 0, 0);
}

__global__ __launch_bounds__(256) void gemm_lse_kernel(const unsigned short* __restrict__ Enb,
                                                       const unsigned short* __restrict__ Cnb,
                                                       float* __restrict__ posArr,
                                                       float* __restrict__ sumexp) {
    __shared__ unsigned short As[2 * CHUNK];   // 16 KB: buf b at As + b*CHUNK
    __shared__ unsigned short Bs[2 * CHUNK];   // 16 KB

    const int tid  = threadIdx.x;
    const int wid  = tid >> 6, lane = tid & 63;
    const int l15  = lane & 15, quad = lane >> 4;
    const int wave_m = wid >> 1, wave_n = wid & 1;

    // XCD-aware bijective swizzle: grid 2560 = 8 XCDs x 320 contiguous blocks.
    // Within an XCD, bn runs fastest -> each A-panel is fetched into ONE XCD's
    // L2 and reused 16x; all B panels (1 MB) stay L2-resident.
    const int swz = (blockIdx.x & 7) * 320 + (blockIdx.x >> 3);
    const int bn = swz & 15;                 // SS/BN = 16
    const int bm = swz >> 4;                 // BB/BM = 160
    const int row0 = bm * BM, n0 = bn * BN;

    // staging map (per chunk): 16 sub-chunks of 1 KB (16 rows x 32k);
    // A: c=0..7, B: c=8..15; 4 per wave. lane -> row rl=lane>>2, slot sl=lane&3;
    // fetch logical granule sl^((rl>>1)&3) (pre-swizzled global source,
    // linear LDS dest -> consistent with the fragment-read swizzle).
    const int rl = lane >> 2;
    const int gf = ((lane & 3) ^ ((rl >> 1) & 3)) * 8;
    const unsigned short* gp[4];
    unsigned short* lp[4];
#pragma unroll
    for (int i = 0; i < 4; ++i) {
        const int c = wid * 4 + i;
        if (c < 8) {
            gp[i] = Enb + (size_t)(row0 + c * 16 + rl) * DD + gf;
            lp[i] = As + c * 512;
        } else {
            gp[i] = Cnb + (size_t)(n0 + (c - 8) * 16 + rl) * DD + gf;
            lp[i] = Bs + (c - 8) * 512;
        }
    }

    // fragment offsets (within a chunk buffer): row r = wtile*16 + l15,
    // elem = r*BK + (quad^((l15>>1)&3))*8  -- verified conflict-free
    const int fswz = (quad ^ ((l15 >> 1) & 3)) * 8;
    int aoff[4], boff[4];
#pragma unroll
    for (int t = 0; t < 4; ++t) {
        aoff[t] = (wave_m * 64 + t * 16 + l15) * BK + fswz;
        boff[t] = (wave_n * 64 + t * 16 + l15) * BK + fswz;
    }

    floatx4 acc[4][4];
#pragma unroll
    for (int i = 0; i < 4; ++i)
#pragma unroll
        for (int j = 0; j < 4; ++j) acc[i][j] = (floatx4){0.f, 0.f, 0.f, 0.f};

    // ---- prologue: stage chunk 0 into buf 0, full drain ----
#pragma unroll
    for (int i = 0; i < 4; ++i) gl_lds16(gp[i], lp[i]);
    __syncthreads();

    // ---- 2-phase K-loop: stage t+1 into buf (t+1)&1, compute t from buf t&1,
    // then ONE __syncthreads (drains vmcnt -> next buffer ready; also protects
    // buf (t+1)&1 reuse: its last readers drained at the PREVIOUS sync). ----
#pragma unroll
    for (int t = 0; t < NCK; ++t) {
        const int buf = t & 1;
        if (t + 1 < NCK) {
#pragma unroll
            for (int i = 0; i < 4; ++i)
                gl_lds16(gp[i] + (t + 1) * BK, lp[i] + ((t + 1) & 1) * CHUNK);
        }
        chunk_mfma(As + buf * CHUNK, Bs + buf * CHUNK, aoff, boff, acc);
        __syncthreads();
    }

    // epilogue: C/D layout col=l15 (n), row=quad*4+reg (m) -- unchanged
#pragma unroll
    for (int mt = 0; mt < 4; ++mt) {
        float rs[4] = {0.f, 0.f, 0.f, 0.f};
        const int growb = row0 + wave_m * 64 + mt * 16 + quad * 4;
#pragma unroll
        for (int nt = 0; nt < 4; ++nt) {
            const int col = n0 + wave_n * 64 + nt * 16 + l15;
#pragma unroll
            for (int r = 0; r < 4; ++r) {
                const int grow = growb + r;
                const float sim = acc[mt][nt][r];
                if (col == grow / UU) {
                    posArr[grow] = sim;           // excluded from sum (-inf mask)
                } else {
                    rs[r] += __expf(sim);
                }
            }
        }
#pragma unroll
        for (int m = 1; m < 16; m <<= 1) {
#pragma unroll
            for (int r = 0; r < 4; ++r) rs[r] += __shfl_xor(rs[r], m, 64);
        }
        if (l15 == 0) {
#pragma unroll
            for (int r = 0; r < 4; ++r) atomicAdd(&sumexp[growb + r], rs[r]);
        }
    }
}

// ---- Kernel 3: single-pass finalize: mean of (-pos + log(sumexp)) ----
__global__ __launch_bounds__(256) void finalize_kernel(const float* __restrict__ posArr,
                                                       const float* __restrict__ sumexp,
                                                       float* __restrict__ out) {
    __shared__ float sred[256];
    const int tid = threadIdx.x;
    const int r = blockIdx.x * 256 + tid;
    sred[tid] = logf(sumexp[r]) - posArr[r];
    __syncthreads();
#pragma unroll
    for (int off = 128; off; off >>= 1) {
        if (tid < off) sred[tid] += sred[tid + off];
        __syncthreads();
    }
    if (tid == 0) atomicAdd(out, sred[0] * (1.0f / (float)BB));
}

extern "C" void kernel_launch(void* const* d_in, const int* in_sizes, int n_in,
                              void* d_out, int out_size, void* d_ws, size_t ws_size,
                              hipStream_t stream) {
    const float* E = (const float*)d_in[0];
    float* out = (float*)d_out;

    unsigned short* Enb = (unsigned short*)d_ws;            // BB*DD bf16 = 10.5 MB
    unsigned short* Cnb = Enb + (size_t)BB * DD;            // SS*DD bf16 = 1 MB
    float* posArr = (float*)(Cnb + (size_t)SS * DD);        // BB floats
    float* sumexp = posArr + BB;                            // BB floats (zeroed by prep)

    prep_kernel<<<SS, 256, 0, stream>>>(E, Enb, Cnb, sumexp, out);
    gemm_lse_kernel<<<(BB / BM) * (SS / BN), 256, 0, stream>>>(Enb, Cnb, posArr, sumexp);
    finalize_kernel<<<BB / 256, 256, 0, stream>>>(posArr, sumexp, out);
}

// Round 3
// 114.038 us; speedup vs baseline: 1.3481x; 1.0556x over previous
//
#include <hip/hip_runtime.h>
#include <math.h>

// Problem constants (setup_inputs: S=2048, U=10, D=256)
#define SS   2048
#define UU   10
#define DD   256
#define BB   (SS * UU)   // 20480 rows
#define EPSF 1e-8f

typedef __attribute__((ext_vector_type(8))) short   bf16x8;
typedef __attribute__((ext_vector_type(4))) float   floatx4;

__device__ static inline unsigned short f2bf(float f) {
    union { float f; unsigned u; } v; v.f = f;
    unsigned r = (v.u + 0x7FFFu + ((v.u >> 16) & 1u)) >> 16;  // RNE
    return (unsigned short)r;
}

__device__ static inline void gl_lds16(const unsigned short* g, unsigned short* l) {
    // 16B per lane; LDS dest = wave-uniform base + lane*16
    __builtin_amdgcn_global_load_lds((const __attribute__((address_space(1))) void*)g,
                                     (__attribute__((address_space(3))) void*)l, 16, 0, 0);
}

// ---- Kernel 1 (fused prep): normalize rows -> Enb, centroid+normalize -> Cnb,
//      zero sumexp (and out) so no memset dispatch is needed ----
__global__ __launch_bounds__(256) void prep_kernel(const float* __restrict__ E,
                                                   unsigned short* __restrict__ Enb,
                                                   unsigned short* __restrict__ Cnb,
                                                   float* __restrict__ sumexp,
                                                   float* __restrict__ out) {
    const int s   = blockIdx.x;
    const int wid = threadIdx.x >> 6, lane = threadIdx.x & 63;
    __shared__ float cent[4][256];
    __shared__ float sred[256];

    if (threadIdx.x < UU) sumexp[s * UU + threadIdx.x] = 0.f;
    if (s == 0 && threadIdx.x == 0) out[0] = 0.f;

    float cp0 = 0.f, cp1 = 0.f, cp2 = 0.f, cp3 = 0.f;
    for (int u = wid; u < UU; u += 4) {
        const size_t roff = (size_t)(s * UU + u) * DD;
        float4 v = ((const float4*)(E + roff))[lane];
        float ssq = v.x * v.x + v.y * v.y + v.z * v.z + v.w * v.w;
#pragma unroll
        for (int off = 32; off; off >>= 1) ssq += __shfl_xor(ssq, off, 64);
        const float rinv = 1.0f / fmaxf(sqrtf(ssq), EPSF);
        ushort4 o;
        o.x = f2bf(v.x * rinv); o.y = f2bf(v.y * rinv);
        o.z = f2bf(v.z * rinv); o.w = f2bf(v.w * rinv);
        ((ushort4*)(Enb + roff))[lane] = o;
        cp0 += v.x; cp1 += v.y; cp2 += v.z; cp3 += v.w;
    }
    cent[wid][lane * 4 + 0] = cp0;
    cent[wid][lane * 4 + 1] = cp1;
    cent[wid][lane * 4 + 2] = cp2;
    cent[wid][lane * 4 + 3] = cp3;
    __syncthreads();

    const int d = threadIdx.x;
    const float c = (cent[0][d] + cent[1][d] + cent[2][d] + cent[3][d]) * 0.1f;
    sred[d] = c * c;
    __syncthreads();
#pragma unroll
    for (int off = 128; off; off >>= 1) {
        if (d < off) sred[d] += sred[d + off];
        __syncthreads();
    }
    const float rinv = 1.0f / fmaxf(sqrtf(sred[0]), EPSF);
    Cnb[(size_t)s * DD + d] = f2bf(c * rinv);
}

// ---- Kernel 2: bf16 MFMA GEMM (Enb x Cnb^T) fused with exp-sum + pos ----
// Round-3 structure: round-0 verified core VERBATIM (128x128 tile, 2x2 waves,
// 4x4 16x16x32 tiles, BK=32 single-buffered, 2 barriers/step, swizzled LDS
// granules) wrapped in an NBN=2 bn-panel loop per block. Rationale: rounds
// 0/1 showed per-block lifetime is ~invariant to staging structure (fixed
// per-block cost dominates); amortize it over 2x the output. Epilogue wins:
// rs accumulates across both panels (atomics per row 32->16, shuffle-reduce
// once/block), labels grow/UU hoisted out of the element loop.
#define BM  128
#define BN  128
#define BK  32
#define NBN 2            // bn panels per block; grid = 160 * (16/NBN) = 1280

__device__ __forceinline__ void chunk_mfma(const unsigned short* Ab,
                                           const unsigned short* Bb,
                                           const int* aoff, const int* boff,
                                           floatx4 (&acc)[4][4]) {
    bf16x8 af[4], bfr[4];
#pragma unroll
    for (int t = 0; t < 4; ++t) af[t]  = *(const bf16x8*)(Ab + aoff[t]);
#pragma unroll
    for (int t = 0; t < 4; ++t) bfr[t] = *(const bf16x8*)(Bb + boff[t]);
#pragma unroll
    for (int mt = 0; mt < 4; ++mt)
#pragma unroll
        for (int nt = 0; nt < 4; ++nt)
            acc[mt][nt] = __builtin_amdgcn_mfma_f32_16x16x32_bf16(af[mt], bfr[nt], acc[mt][nt], 0, 0, 0);
}

__global__ __launch_bounds__(256) void gemm_lse_kernel(const unsigned short* __restrict__ Enb,
                                                       const unsigned short* __restrict__ Cnb,
                                                       float* __restrict__ posArr,
                                                       float* __restrict__ sumexp) {
    __shared__ unsigned short As[BM * BK];   // 8 KB, single-buffered (round-0)
    __shared__ unsigned short Bs[BN * BK];   // 8 KB

    const int tid  = threadIdx.x;
    const int wid  = tid >> 6, lane = tid & 63;
    const int l15  = lane & 15, quad = lane >> 4;
    const int wave_m = wid >> 1, wave_n = wid & 1;

    // A-grouped order (round-0 spirit): consecutive blocks share the A panel.
    const int bm  = blockIdx.x >> 3;          // BB/BM = 160
    const int bnb = (blockIdx.x & 7) * NBN;   // 8 bn-groups of NBN panels
    const int row0 = bm * BM;

    // staging map (per chunk): 16 sub-chunks of 1 KB (16 rows x 32k);
    // A: c=0..7, B: c=8..15; 4 per wave. lane -> row rl=lane>>2, slot sl=lane&3;
    // fetch logical granule sl^((rl>>1)&3) (pre-swizzled global source,
    // linear LDS dest -> consistent with the fragment-read swizzle).
    const int rl = lane >> 2;
    const int gf = ((lane & 3) ^ ((rl >> 1) & 3)) * 8;
    const unsigned short* gpA[4];
    unsigned short* lp[4];
    size_t goffB[4];
#pragma unroll
    for (int i = 0; i < 4; ++i) {
        const int c = wid * 4 + i;
        if (c < 8) {
            gpA[i]  = Enb + (size_t)(row0 + c * 16 + rl) * DD + gf;
            lp[i]   = As + c * 512;
            goffB[i] = 0;
        } else {
            gpA[i]  = nullptr;
            lp[i]   = Bs + (c - 8) * 512;
            goffB[i] = (size_t)((c - 8) * 16 + rl) * DD + gf;
        }
    }

    // fragment offsets: row r = wtile*16 + l15, elem = r*BK + (quad^((l15>>1)&3))*8
    const int fswz = (quad ^ ((l15 >> 1) & 3)) * 8;
    int aoff[4], boff[4];
#pragma unroll
    for (int t = 0; t < 4; ++t) {
        aoff[t] = (wave_m * 64 + t * 16 + l15) * BK + fswz;
        boff[t] = (wave_n * 64 + t * 16 + l15) * BK + fswz;
    }

    // hoisted labels + cross-panel exp accumulators
    int lbl[4][4];
    float rs[4][4];
#pragma unroll
    for (int mt = 0; mt < 4; ++mt) {
        const int growb = row0 + wave_m * 64 + mt * 16 + quad * 4;
#pragma unroll
        for (int r = 0; r < 4; ++r) {
            lbl[mt][r] = (growb + r) / UU;
            rs[mt][r]  = 0.f;
        }
    }

    floatx4 acc[4][4];

#pragma unroll
    for (int bl = 0; bl < NBN; ++bl) {
        const int n0 = (bnb + bl) * BN;
        const unsigned short* gp[4];
#pragma unroll
        for (int i = 0; i < 4; ++i) {
            const int c = wid * 4 + i;
            gp[i] = (c < 8) ? gpA[i] : (Cnb + (size_t)n0 * DD + goffB[i]);
        }

#pragma unroll
        for (int i = 0; i < 4; ++i)
#pragma unroll
            for (int j = 0; j < 4; ++j) acc[i][j] = (floatx4){0.f, 0.f, 0.f, 0.f};

        // round-0 K-loop verbatim: sync; stage; sync; compute
        for (int k0 = 0; k0 < DD; k0 += BK) {
            __syncthreads();                      // prior LDS reads done
#pragma unroll
            for (int i = 0; i < 4; ++i) gl_lds16(gp[i] + k0, lp[i]);
            __syncthreads();                      // vmcnt drained: tiles landed
            chunk_mfma(As, Bs, aoff, boff, acc);
        }

        // per-panel epilogue: exp-accumulate into rs (register, cross-panel)
#pragma unroll
        for (int mt = 0; mt < 4; ++mt) {
            const int growb = row0 + wave_m * 64 + mt * 16 + quad * 4;
#pragma unroll
            for (int nt = 0; nt < 4; ++nt) {
                const int col = n0 + wave_n * 64 + nt * 16 + l15;
#pragma unroll
                for (int r = 0; r < 4; ++r) {
                    const float sim = acc[mt][nt][r];
                    if (col == lbl[mt][r]) {
                        posArr[growb + r] = sim;     // excluded from sum
                    } else {
                        rs[mt][r] += __expf(sim);
                    }
                }
            }
        }
    }

    // once-per-block reduce + atomics (C/D layout: col=l15, row=quad*4+reg)
#pragma unroll
    for (int mt = 0; mt < 4; ++mt) {
        const int growb = row0 + wave_m * 64 + mt * 16 + quad * 4;
#pragma unroll
        for (int m = 1; m < 16; m <<= 1) {
#pragma unroll
            for (int r = 0; r < 4; ++r) rs[mt][r] += __shfl_xor(rs[mt][r], m, 64);
        }
        if (l15 == 0) {
#pragma unroll
            for (int r = 0; r < 4; ++r) atomicAdd(&sumexp[growb + r], rs[mt][r]);
        }
    }
}

// ---- Kernel 3: single-pass finalize: mean of (-pos + log(sumexp)) ----
__global__ __launch_bounds__(256) void finalize_kernel(const float* __restrict__ posArr,
                                                       const float* __restrict__ sumexp,
                                                       float* __restrict__ out) {
    __shared__ float sred[256];
    const int tid = threadIdx.x;
    const int r = blockIdx.x * 256 + tid;
    sred[tid] = logf(sumexp[r]) - posArr[r];
    __syncthreads();
#pragma unroll
    for (int off = 128; off; off >>= 1) {
        if (tid < off) sred[tid] += sred[tid + off];
        __syncthreads();
    }
    if (tid == 0) atomicAdd(out, sred[0] * (1.0f / (float)BB));
}

extern "C" void kernel_launch(void* const* d_in, const int* in_sizes, int n_in,
                              void* d_out, int out_size, void* d_ws, size_t ws_size,
                              hipStream_t stream) {
    const float* E = (const float*)d_in[0];
    float* out = (float*)d_out;

    unsigned short* Enb = (unsigned short*)d_ws;            // BB*DD bf16 = 10.5 MB
    unsigned short* Cnb = Enb + (size_t)BB * DD;            // SS*DD bf16 = 1 MB
    float* posArr = (float*)(Cnb + (size_t)SS * DD);        // BB floats
    float* sumexp = posArr + BB;                            // BB floats (zeroed by prep)

    prep_kernel<<<SS, 256, 0, stream>>>(E, Enb, Cnb, sumexp, out);
    gemm_lse_kernel<<<(BB / BM) * (SS / BN / NBN), 256, 0, stream>>>(Enb, Cnb, posArr, sumexp);
    finalize_kernel<<<BB / 256, 256, 0, stream>>>(posArr, sumexp, out);
}